// Round 3
// baseline (717.287 us; speedup 1.0000x reference)
//
#include <hip/hip_runtime.h>
#include <math.h>

static constexpr int   kB = 4096;
static constexpr int   kG = 512;
static constexpr int   kD = 64;
static constexpr int   kP = kG * kD;        // 32768 features
static constexpr int   kYB = kB / 256;      // 16 row-blocks (fallback path)
static constexpr int   kStrips = 64;        // stats strips (64 rows each)
static constexpr float kEps   = 1e-5f;
static constexpr float kSlope = 0.2f;

// ---------------------------------------------------------------------------
// idx identity checker: verifies idx[e] == e (under int32/int64 word-stride
// heuristic). Sets flag!=0 if any mismatch -> pass1 takes gather path.
// NOTE: idx is arange in the reference setup; the heuristic stride detection
// (int64 LE low-words vs int32) is only ambiguous for adversarial non-arange
// int32 data, which cannot occur here.
// ---------------------------------------------------------------------------
__global__ __launch_bounds__(256) void k_idxcheck(const int* __restrict__ idxw,
                                                  int* __restrict__ flag) {
    const int e = blockIdx.x * 256 + threadIdx.x;
    const int wstride = (idxw[1] == 0 && idxw[2] == 1) ? 2 : 1;
    bool ok = (idxw[(size_t)e * wstride] == e);
    if (wstride == 2) ok = ok && (idxw[(size_t)e * 2 + 1] == 0);
    if (!ok) atomicOr(flag, 1);
}

// ---------------------------------------------------------------------------
// Pass 1 (streaming): one wave per (row, half-row). Each wave reads 64 KiB of
// x fully sequentially (64 x 1 KiB coalesced float4 loads) -> max DRAM page
// locality. Per 1 KiB chunk (256 floats = 4 groups of D=64), a 4-step
// shfl_xor(…,16) segmented reduce produces 4 group dots; LeakyReLU; lanes
// s==0 store 4 contiguous floats of reps[row]. W re-read per row (L2/LLC-hot).
// Grid 2048 blocks x 256 thr (4 waves) = 8192 waves = 2 per row.
// ---------------------------------------------------------------------------
__global__ __launch_bounds__(256) void p1_stream(const float* __restrict__ x,
                                                 const int*   __restrict__ idxw,
                                                 const float* __restrict__ W,
                                                 const int*   __restrict__ flag,
                                                 float* __restrict__ reps) {
    const int tid  = threadIdx.x;
    const int w    = tid >> 6;
    const int lane = tid & 63;
    const int seg  = lane >> 4;
    const int s    = lane & 15;

    const int waveG = blockIdx.x * 4 + w;
    const int row   = waveG >> 1;
    const int half  = waveG & 1;
    const int colbase = half * (kP / 2);    // 16384 floats

    float* rp = reps + (size_t)row * kG + half * (kG / 2);

    if (flag[0] == 0) {
        const float4* xp = (const float4*)(x + (size_t)row * kP + colbase) + lane;
        const float4* wp = (const float4*)(W + colbase) + lane;
        #pragma unroll 8
        for (int i = 0; i < 64; ++i) {
            const float4 xv = xp[i * 64];
            const float4 wv = wp[i * 64];
            float dot = xv.x * wv.x + xv.y * wv.y + xv.z * wv.z + xv.w * wv.w;
            dot += __shfl_xor(dot, 1, 16);
            dot += __shfl_xor(dot, 2, 16);
            dot += __shfl_xor(dot, 4, 16);
            dot += __shfl_xor(dot, 8, 16);
            const float v = dot >= 0.f ? dot : kSlope * dot;
            if (s == 0) rp[i * 4 + seg] = v;   // 4 lanes -> one 16B transaction
        }
    } else {
        // general gather path (arbitrary idx)
        const int wstride = (idxw[1] == 0 && idxw[2] == 1) ? 2 : 1;
        const float* xr = x + (size_t)row * kP;
        for (int i = 0; i < 64; ++i) {
            const int e = colbase + i * 256 + lane * 4;
            const int f0 = idxw[(size_t)(e + 0) * wstride];
            const int f1 = idxw[(size_t)(e + 1) * wstride];
            const int f2 = idxw[(size_t)(e + 2) * wstride];
            const int f3 = idxw[(size_t)(e + 3) * wstride];
            const float4 wv = *(const float4*)(W + e);
            float dot = xr[f0] * wv.x + xr[f1] * wv.y + xr[f2] * wv.z +
                        xr[f3] * wv.w;
            dot += __shfl_xor(dot, 1, 16);
            dot += __shfl_xor(dot, 2, 16);
            dot += __shfl_xor(dot, 4, 16);
            dot += __shfl_xor(dot, 8, 16);
            const float v = dot >= 0.f ? dot : kSlope * dot;
            if (s == 0) rp[i * 4 + seg] = v;
        }
    }
}

// ---------------------------------------------------------------------------
// Pass 2a: per-strip (64 rows) group sums from reps. 64 blocks x 256 thr.
// Coalesced reads (consecutive threads -> consecutive g). LLC-hot.
// ---------------------------------------------------------------------------
__global__ __launch_bounds__(256) void p2_strip(const float* __restrict__ reps,
                                                float* __restrict__ psum,
                                                float* __restrict__ psumsq) {
    const int j = blockIdx.x;
    const int t = threadIdx.x;
    #pragma unroll
    for (int c = 0; c < 2; ++c) {
        const int g = c * 256 + t;
        const float* rp = reps + (size_t)j * 64 * kG + g;
        float s = 0.f, ss = 0.f;
        #pragma unroll 8
        for (int r = 0; r < 64; ++r) {
            const float v = rp[(size_t)r * kG];
            s += v; ss += v * v;
        }
        psum  [(size_t)j * kG + g] = s;
        psumsq[(size_t)j * kG + g] = ss;
    }
}

// ---------------------------------------------------------------------------
// Pass 2b: reduce strips, fold BN + fc into per-group affine:
//   a[g] = fc_w[g]*gamma[g]*rsqrt(var+eps)
//   c    = fc_b + sum_g fc_w[g]*(beta[g] - gamma[g]*mean[g]*rsqrt(var+eps))
// ---------------------------------------------------------------------------
__global__ __launch_bounds__(kG) void p2_final(const float* __restrict__ psum,
                                               const float* __restrict__ psumsq,
                                               const float* __restrict__ gamma,
                                               const float* __restrict__ beta,
                                               const float* __restrict__ fcw,
                                               const float* __restrict__ fcb,
                                               float* __restrict__ acoef,
                                               float* __restrict__ cval) {
    const int g = threadIdx.x;
    float s = 0.f, ss = 0.f;
    #pragma unroll 8
    for (int y = 0; y < kStrips; ++y) {
        s  += psum  [(size_t)y * kG + g];
        ss += psumsq[(size_t)y * kG + g];
    }
    const float invB = 1.0f / (float)kB;
    const float mean = s * invB;
    float var = ss * invB - mean * mean;
    var = var < 0.f ? 0.f : var;
    const float rs = rsqrtf(var + kEps);
    const float fw = fcw[g];
    const float ga = gamma[g];
    acoef[g] = fw * ga * rs;
    float cg = fw * (beta[g] - ga * mean * rs);

    __shared__ float red[kG];
    red[g] = cg;
    __syncthreads();
    for (int off = kG / 2; off > 0; off >>= 1) {
        if (g < off) red[g] += red[g + off];
        __syncthreads();
    }
    if (g == 0) cval[0] = red[0] + fcb[0];
}

// ---------------------------------------------------------------------------
// Pass 3: out[b] = sigmoid(sum_g a[g]*reps[b,g] + c). One wave per row.
// ---------------------------------------------------------------------------
__global__ __launch_bounds__(256) void pass3(const float* __restrict__ reps,
                                             const float* __restrict__ acoef,
                                             const float* __restrict__ cval,
                                             float* __restrict__ out) {
    const int tid  = threadIdx.x;
    const int w    = tid >> 6;
    const int lane = tid & 63;
    const int b    = blockIdx.x * 4 + w;
    const float* r = reps + (size_t)b * kG;

    float acc = 0.f;
    #pragma unroll
    for (int c = 0; c < 2; ++c) {
        const int o = c * 256 + lane * 4;
        const float4 rv = *(const float4*)(r + o);
        const float4 av = *(const float4*)(acoef + o);
        acc += rv.x * av.x + rv.y * av.y + rv.z * av.z + rv.w * av.w;
    }
    acc += __shfl_xor(acc, 1, 64);
    acc += __shfl_xor(acc, 2, 64);
    acc += __shfl_xor(acc, 4, 64);
    acc += __shfl_xor(acc, 8, 64);
    acc += __shfl_xor(acc, 16, 64);
    acc += __shfl_xor(acc, 32, 64);
    if (lane == 0) {
        const float logit = acc + cval[0];
        out[b] = 1.f / (1.f + expf(-logit));
    }
}

// ---------------------------------------------------------------------------
// Small-workspace fallback path (previous round's kernels, kept for safety).
// ---------------------------------------------------------------------------
template<bool STORE_REPS>
__global__ __launch_bounds__(256) void pass1_old(const float* __restrict__ x,
                                                 const int*   __restrict__ idxw,
                                                 const float* __restrict__ W,
                                                 float* __restrict__ reps,
                                                 float* __restrict__ psum,
                                                 float* __restrict__ psumsq) {
    const int tid  = threadIdx.x;
    const int w    = tid >> 6;
    const int lane = tid & 63;
    const int seg  = lane >> 4;
    const int s    = lane & 15;
    const int q    = blockIdx.x;
    const int g    = 4 * q + seg;
    const int base = g * 64 + 4 * s;

    const int wstride = (idxw[1] == 0 && idxw[2] == 1) ? 2 : 1;
    const int f0 = idxw[(size_t)(base + 0) * wstride];
    const int f1 = idxw[(size_t)(base + 1) * wstride];
    const int f2 = idxw[(size_t)(base + 2) * wstride];
    const int f3 = idxw[(size_t)(base + 3) * wstride];
    const float4 wv = *(const float4*)(W + base);

    const int row0 = blockIdx.y * 256 + w * 64;
    float asum = 0.f, asq = 0.f;
    #pragma unroll 2
    for (int i = 0; i < 64; ++i) {
        const int b = row0 + i;
        const float* xr = x + (size_t)b * kP;
        float dot = xr[f0] * wv.x + xr[f1] * wv.y + xr[f2] * wv.z + xr[f3] * wv.w;
        dot += __shfl_xor(dot, 1, 16);
        dot += __shfl_xor(dot, 2, 16);
        dot += __shfl_xor(dot, 4, 16);
        dot += __shfl_xor(dot, 8, 16);
        const float v = dot >= 0.f ? dot : kSlope * dot;
        if (s == 0) {
            if (STORE_REPS) reps[(size_t)b * kG + g] = v;
            asum += v; asq += v * v;
        }
    }
    __shared__ float ls[4][4];
    __shared__ float lq[4][4];
    if (s == 0) { ls[w][seg] = asum; lq[w][seg] = asq; }
    __syncthreads();
    if (tid < 4) {
        const int gg = 4 * q + tid;
        psum  [(size_t)blockIdx.y * kG + gg] = ls[0][tid] + ls[1][tid] + ls[2][tid] + ls[3][tid];
        psumsq[(size_t)blockIdx.y * kG + gg] = lq[0][tid] + lq[1][tid] + lq[2][tid] + lq[3][tid];
    }
}

__global__ __launch_bounds__(kG) void pass2_old(const float* __restrict__ psum,
                                                const float* __restrict__ psumsq,
                                                const float* __restrict__ gamma,
                                                const float* __restrict__ beta,
                                                const float* __restrict__ fcw,
                                                const float* __restrict__ fcb,
                                                float* __restrict__ acoef,
                                                float* __restrict__ cval) {
    const int g = threadIdx.x;
    float s = 0.f, ss = 0.f;
    #pragma unroll
    for (int y = 0; y < kYB; ++y) {
        s  += psum  [(size_t)y * kG + g];
        ss += psumsq[(size_t)y * kG + g];
    }
    const float invB = 1.0f / (float)kB;
    const float mean = s * invB;
    float var = ss * invB - mean * mean;
    var = var < 0.f ? 0.f : var;
    const float rs = rsqrtf(var + kEps);
    const float fw = fcw[g];
    const float ga = gamma[g];
    acoef[g] = fw * ga * rs;
    float cg = fw * (beta[g] - ga * mean * rs);

    __shared__ float red[kG];
    red[g] = cg;
    __syncthreads();
    for (int off = kG / 2; off > 0; off >>= 1) {
        if (g < off) red[g] += red[g + off];
        __syncthreads();
    }
    if (g == 0) cval[0] = red[0] + fcb[0];
}

__global__ __launch_bounds__(256) void pass3_re(const float* __restrict__ x,
                                                const int*   __restrict__ idxw,
                                                const float* __restrict__ W,
                                                const float* __restrict__ acoef,
                                                float* __restrict__ logit) {
    const int tid  = threadIdx.x;
    const int w    = tid >> 6;
    const int lane = tid & 63;
    const int seg  = lane >> 4;
    const int s    = lane & 15;
    const int q    = blockIdx.x;
    const int g    = 4 * q + seg;
    const int base = g * 64 + 4 * s;

    const int wstride = (idxw[1] == 0 && idxw[2] == 1) ? 2 : 1;
    const int f0 = idxw[(size_t)(base + 0) * wstride];
    const int f1 = idxw[(size_t)(base + 1) * wstride];
    const int f2 = idxw[(size_t)(base + 2) * wstride];
    const int f3 = idxw[(size_t)(base + 3) * wstride];
    const float4 wv = *(const float4*)(W + base);
    const float ag = acoef[g];

    const int row0 = blockIdx.y * 256 + w * 64;
    for (int i = 0; i < 64; ++i) {
        const int b = row0 + i;
        const float* xr = x + (size_t)b * kP;
        float dot = xr[f0] * wv.x + xr[f1] * wv.y + xr[f2] * wv.z + xr[f3] * wv.w;
        dot += __shfl_xor(dot, 1, 16);
        dot += __shfl_xor(dot, 2, 16);
        dot += __shfl_xor(dot, 4, 16);
        dot += __shfl_xor(dot, 8, 16);
        const float v = dot >= 0.f ? dot : kSlope * dot;
        float t = (s == 0) ? ag * v : 0.f;
        t += __shfl_xor(t, 16, 64);
        t += __shfl_xor(t, 32, 64);
        if (lane == 0) atomicAdd(&logit[b], t);
    }
}

__global__ __launch_bounds__(256) void pass4(const float* __restrict__ logit,
                                             const float* __restrict__ cval,
                                             float* __restrict__ out) {
    const int b = blockIdx.x * 256 + threadIdx.x;
    const float l = logit[b] + cval[0];
    out[b] = 1.f / (1.f + expf(-l));
}

// ---------------------------------------------------------------------------
extern "C" void kernel_launch(void* const* d_in, const int* in_sizes, int n_in,
                              void* d_out, int out_size, void* d_ws,
                              size_t ws_size, hipStream_t stream) {
    const float* x     = (const float*)d_in[0];
    const int*   idxw  = (const int*)  d_in[1];
    const float* W     = (const float*)d_in[2];
    const float* gamma = (const float*)d_in[3];
    const float* beta  = (const float*)d_in[4];
    const float* fcw   = (const float*)d_in[5];
    const float* fcb   = (const float*)d_in[6];
    float* out = (float*)d_out;

    const size_t need_fast =
        ((size_t)kB * kG + 2 * (size_t)kStrips * kG + kG + 8) * sizeof(float);

    if (ws_size >= need_fast) {
        float* reps   = (float*)d_ws;
        float* psum   = reps + (size_t)kB * kG;
        float* psumsq = psum + (size_t)kStrips * kG;
        float* acoef  = psumsq + (size_t)kStrips * kG;
        float* cval   = acoef + kG;
        int*   flag   = (int*)(cval + 4);

        hipMemsetAsync(flag, 0, sizeof(int), stream);
        k_idxcheck<<<kP / 256, 256, 0, stream>>>(idxw, flag);
        p1_stream<<<kB * 2 / 4, 256, 0, stream>>>(x, idxw, W, flag, reps);
        p2_strip<<<kStrips, 256, 0, stream>>>(reps, psum, psumsq);
        p2_final<<<1, kG, 0, stream>>>(psum, psumsq, gamma, beta, fcw, fcb,
                                       acoef, cval);
        pass3<<<kB / 4, 256, 0, stream>>>(reps, acoef, cval, out);
    } else {
        float* psum   = (float*)d_ws;
        float* psumsq = psum + (size_t)kYB * kG;
        float* acoef  = psumsq + (size_t)kYB * kG;
        float* cval   = acoef + kG;
        float* logit  = cval + 4;
        hipMemsetAsync(logit, 0, kB * sizeof(float), stream);
        pass1_old<false><<<dim3(kG / 4, kYB), 256, 0, stream>>>(
            x, idxw, W, nullptr, psum, psumsq);
        pass2_old<<<1, kG, 0, stream>>>(psum, psumsq, gamma, beta, fcw, fcb,
                                        acoef, cval);
        pass3_re<<<dim3(kG / 4, kYB), 256, 0, stream>>>(x, idxw, W, acoef, logit);
        pass4<<<kB / 256, 256, 0, stream>>>(logit, cval, out);
    }
}